// Round 4
// baseline (4832.178 us; speedup 1.0000x reference)
//
#include <hip/hip_runtime.h>

// FFJORD B=4096 D=64 C=16 H=512, NBIJ=2, NSTEPS=8 RK4 -> 64 sequential MLP+VJP evals.
// Round 4: Round-2 code shape (128 VGPR, no spills) + 2 blocks/CU for TLP:
// M=8 rows/block, grid=512, 512 threads (8 waves). MFMA tiles half-empty in M
// (A rows 8..15 zeroed; C rows independent). LDS ~65.9KB -> 2 blocks/CU resident.

typedef __attribute__((ext_vector_type(8))) short short8;
typedef __attribute__((ext_vector_type(4))) float f32x4;

#define MFMA_B16(a, b, c) __builtin_amdgcn_mfma_f32_16x16x32_bf16((a), (b), (c), 0, 0, 0)

__device__ __forceinline__ unsigned short f2bf(float f) {
  union { float f; unsigned u; } v; v.f = f;
  return (unsigned short)((v.u + 0x7FFFu + ((v.u >> 16) & 1u)) >> 16);
}
__device__ __forceinline__ float bf2f(unsigned short u) {
  union { unsigned u; float f; } v; v.u = ((unsigned)u) << 16; return v.f;
}
__device__ __forceinline__ float fast_tanh(float x) {
  float e = __expf(2.f * x);
  return 1.f - 2.f * __builtin_amdgcn_rcpf(e + 1.f);
}

// ws layout (ushort units), all bf16 column-major W[n][k]:
// W1f [2][512][96]  @ 0        (k>=81 zero-padded)
// W2f [2][512][512] @ 98304    (W2^T data: forward B)
// W2b [2][512][512] @ 622592   (plain W2: backward B)
// W3f [2][64][512]  @ 1146880  (W3^T: forward B)
// W3b [2][512][64]  @ 1212416  (plain W3: backward B)
// W1y [2][64][512]  @ 1277952  (first 64 rows of W1)

__global__ void prep_bf16(const float* __restrict__ W1, const float* __restrict__ W2,
                          const float* __restrict__ W3, unsigned short* __restrict__ ws) {
  int o = blockIdx.x * 256 + threadIdx.x;
  if (o < 98304) {
    int ib = o / 49152, r = o % 49152, n = r / 96, k = r % 96;
    ws[o] = (k < 81) ? f2bf(W1[(size_t)ib * 41472 + k * 512 + n]) : (unsigned short)0;
  } else if (o < 622592) {
    int o2 = o - 98304;
    int ib = o2 / 262144, r = o2 % 262144, n = r / 512, k = r % 512;
    ws[o] = f2bf(W2[(size_t)ib * 262144 + k * 512 + n]);
  } else if (o < 1146880) {
    ws[o] = f2bf(W2[o - 622592]);
  } else if (o < 1212416) {
    int o2 = o - 1146880;
    int ib = o2 / 32768, r = o2 % 32768, n = r / 512, k = r % 512;
    ws[o] = f2bf(W3[(size_t)ib * 32768 + k * 64 + n]);
  } else if (o < 1277952) {
    ws[o] = f2bf(W3[o - 1212416]);
  } else if (o < 1343488) {
    int o2 = o - 1277952;
    int ib = o2 / 32768, r = o2 % 32768, n = r / 512, k = r % 512;
    ws[o] = f2bf(W1[(size_t)ib * 41472 + n * 512 + k]);
  }
}

#define ZS 104   // z A-buffer stride (K=96 used)
#define HS 520   // h buffers stride (K=512)
#define ES 72    // eps stride (K=64)

__global__ __launch_bounds__(512) void ffjord_mfma(
    const float* __restrict__ x, const float* __restrict__ cond, const float* __restrict__ eps,
    const float* __restrict__ b1g, const float* __restrict__ b2g, const float* __restrict__ b3g,
    const unsigned short* __restrict__ ws, float* __restrict__ out) {
  __shared__ unsigned short zA[16 * ZS];
  __shared__ unsigned short h1A[16 * HS];   // h1; overwritten by g1 in GEMM4b
  __shared__ unsigned short h2A[16 * HS];
  __shared__ unsigned short g2A[16 * HS];
  __shared__ unsigned short epsA[16 * ES];
  __shared__ float eps_s[8][64];
  __shared__ float f_s[8][64];
  __shared__ float ycur[8][64], ytmp[8][64], yacc[8][64];
  __shared__ float l_row[8], ld_row[8], ldacc[8];

  const int t = threadIdx.x;
  const int wave = t >> 6;
  const int lane = t & 63;
  const int lane15 = lane & 15;
  const int q8 = (lane >> 4) * 8;       // frag k-offset; C/D row base = q8>>1
  const int row0 = blockIdx.x * 8;
  const int ws64 = wave * 64;
  const int tm = t >> 6, td = t & 63;   // thread-own element (512 = 8x64)

  // init: state rows 0..7; zero MFMA A-rows 8..15 of zA/epsA (C rows are independent,
  // so zero A-rows keep garbage out; rows 8..15 of h1A/h2A/g2A get bounded junk, unused)
  {
    float xv = x[(size_t)(row0 + tm) * 64 + td];
    ycur[tm][td] = xv; ytmp[tm][td] = xv;
  }
  for (int e = t; e < 8 * ZS; e += 512) zA[8 * ZS + e] = 0;
  for (int e = t; e < 8 * ES; e += 512) epsA[8 * ES + e] = 0;
  if (t < 256) {
    int m = t >> 5, kk = t & 31;   // rows 0..7, cols 64..95
    zA[m * ZS + 64 + kk] = (kk < 16) ? f2bf(cond[(size_t)(row0 + m) * 16 + kk]) : (unsigned short)0;
  }
  if (t < 8) ld_row[t] = 0.f;

  const float dt = 0.125f;
  const float w06 = dt / 6.f, w13 = dt / 3.f;

  for (int ib = 0; ib < 2; ++ib) {
    const unsigned short* W1f = ws + 0       + ib * 49152;
    const unsigned short* W2f = ws + 98304   + ib * 262144;
    const unsigned short* W2b = ws + 622592  + ib * 262144;
    const unsigned short* W3f = ws + 1146880 + ib * 32768;
    const unsigned short* W3b = ws + 1212416 + ib * 32768;
    const unsigned short* W1y = ws + 1277952 + ib * 32768;
    const float* b1b = b1g + ib * 512;
    const float* b2b = b2g + ib * 512;
    const float* b3b = b3g + ib * 64;

    {
      float ev = eps[((size_t)ib * 4096 + row0 + tm) * 64 + td];
      eps_s[tm][td] = ev;
      epsA[tm * ES + td] = f2bf(ev);
    }
    __syncthreads();

    for (int it = 0; it < 32; ++it) {
      const int s = it & 3;
      const float te = (it >> 2) * dt + ((s == 0) ? 0.f : (s == 3) ? dt : 0.5f * dt);

      // ---- z build + zero accumulators ----
      zA[tm * ZS + td] = f2bf(ytmp[tm][td]);
      f_s[tm][td] = 0.f;
      if (t < 8) { zA[t * ZS + 80] = f2bf(te); l_row[t] = 0.f; }
      __syncthreads();

      // ---- GEMM1: h1 = tanh(z @ W1 + b1), K=96, N=512 ----
      {
        f32x4 a0 = {0,0,0,0}, a1 = {0,0,0,0}, a2 = {0,0,0,0}, a3 = {0,0,0,0};
        const unsigned short* ap = zA + lane15 * ZS + q8;
        const unsigned short* wp = W1f + (size_t)(ws64 + lane15) * 96 + q8;
        #pragma unroll
        for (int k0 = 0; k0 < 96; k0 += 32) {
          short8 a = *(const short8*)(ap + k0);
          a0 = MFMA_B16(a, *(const short8*)(wp + k0),           a0);
          a1 = MFMA_B16(a, *(const short8*)(wp + 16 * 96 + k0), a1);
          a2 = MFMA_B16(a, *(const short8*)(wp + 32 * 96 + k0), a2);
          a3 = MFMA_B16(a, *(const short8*)(wp + 48 * 96 + k0), a3);
        }
        f32x4 acc[4] = {a0, a1, a2, a3};
        #pragma unroll
        for (int tl = 0; tl < 4; ++tl) {
          int n = ws64 + tl * 16 + lane15;
          float bias = b1b[n];
          #pragma unroll
          for (int rg = 0; rg < 4; ++rg)
            h1A[((q8 >> 1) + rg) * HS + n] = f2bf(fast_tanh(acc[tl][rg] + bias));
        }
      }
      __syncthreads();

      // ---- GEMM2: h2 = tanh(h1 @ W2 + b2), K=512, N=512 ----
      {
        f32x4 a0 = {0,0,0,0}, a1 = {0,0,0,0}, a2 = {0,0,0,0}, a3 = {0,0,0,0};
        const unsigned short* ap = h1A + lane15 * HS + q8;
        const unsigned short* wp = W2f + (size_t)(ws64 + lane15) * 512 + q8;
        #pragma unroll 4
        for (int k0 = 0; k0 < 512; k0 += 32) {
          short8 a = *(const short8*)(ap + k0);
          a0 = MFMA_B16(a, *(const short8*)(wp + k0),            a0);
          a1 = MFMA_B16(a, *(const short8*)(wp + 16 * 512 + k0), a1);
          a2 = MFMA_B16(a, *(const short8*)(wp + 32 * 512 + k0), a2);
          a3 = MFMA_B16(a, *(const short8*)(wp + 48 * 512 + k0), a3);
        }
        f32x4 acc[4] = {a0, a1, a2, a3};
        #pragma unroll
        for (int tl = 0; tl < 4; ++tl) {
          int n = ws64 + tl * 16 + lane15;
          float bias = b2b[n];
          #pragma unroll
          for (int rg = 0; rg < 4; ++rg)
            h2A[((q8 >> 1) + rg) * HS + n] = f2bf(fast_tanh(acc[tl][rg] + bias));
        }
      }
      __syncthreads();

      // ---- GEMM3f: f += h2 @ W3f (N=64, K split 8 ways x 64) ----
      {
        f32x4 a0 = {0,0,0,0}, a1 = {0,0,0,0}, a2 = {0,0,0,0}, a3 = {0,0,0,0};
        const unsigned short* ap = h2A + lane15 * HS + ws64 + q8;
        const unsigned short* wp = W3f + (size_t)lane15 * 512 + ws64 + q8;
        #pragma unroll
        for (int kk = 0; kk < 64; kk += 32) {
          short8 a = *(const short8*)(ap + kk);
          a0 = MFMA_B16(a, *(const short8*)(wp + kk),            a0);
          a1 = MFMA_B16(a, *(const short8*)(wp + 16 * 512 + kk), a1);
          a2 = MFMA_B16(a, *(const short8*)(wp + 32 * 512 + kk), a2);
          a3 = MFMA_B16(a, *(const short8*)(wp + 48 * 512 + kk), a3);
        }
        f32x4 acc[4] = {a0, a1, a2, a3};
        if (lane < 32) {   // C rows 0..7 only
          #pragma unroll
          for (int tl = 0; tl < 4; ++tl)
            #pragma unroll
            for (int rg = 0; rg < 4; ++rg)
              atomicAdd(&f_s[(q8 >> 1) + rg][tl * 16 + lane15], acc[tl][rg]);
        }
      }
      // ---- GEMM3b: g2 = (eps @ W3^T) * (1 - h2^2), N=512, K=64 ----
      {
        f32x4 a0 = {0,0,0,0}, a1 = {0,0,0,0}, a2 = {0,0,0,0}, a3 = {0,0,0,0};
        const unsigned short* ap = epsA + lane15 * ES + q8;
        const unsigned short* wp = W3b + (size_t)(ws64 + lane15) * 64 + q8;
        #pragma unroll
        for (int kk = 0; kk < 64; kk += 32) {
          short8 a = *(const short8*)(ap + kk);
          a0 = MFMA_B16(a, *(const short8*)(wp + kk),           a0);
          a1 = MFMA_B16(a, *(const short8*)(wp + 16 * 64 + kk), a1);
          a2 = MFMA_B16(a, *(const short8*)(wp + 32 * 64 + kk), a2);
          a3 = MFMA_B16(a, *(const short8*)(wp + 48 * 64 + kk), a3);
        }
        f32x4 acc[4] = {a0, a1, a2, a3};
        #pragma unroll
        for (int tl = 0; tl < 4; ++tl) {
          int n = ws64 + tl * 16 + lane15;
          #pragma unroll
          for (int rg = 0; rg < 4; ++rg) {
            int m = (q8 >> 1) + rg;
            float h = bf2f(h2A[m * HS + n]);
            g2A[m * HS + n] = f2bf(acc[tl][rg] * (1.f - h * h));
          }
        }
      }
      __syncthreads();

      // ---- GEMM4b: g1 = (g2 @ W2^T) * (1 - h1^2) -> h1A in place ----
      {
        f32x4 a0 = {0,0,0,0}, a1 = {0,0,0,0}, a2 = {0,0,0,0}, a3 = {0,0,0,0};
        const unsigned short* ap = g2A + lane15 * HS + q8;
        const unsigned short* wp = W2b + (size_t)(ws64 + lane15) * 512 + q8;
        #pragma unroll 4
        for (int k0 = 0; k0 < 512; k0 += 32) {
          short8 a = *(const short8*)(ap + k0);
          a0 = MFMA_B16(a, *(const short8*)(wp + k0),            a0);
          a1 = MFMA_B16(a, *(const short8*)(wp + 16 * 512 + k0), a1);
          a2 = MFMA_B16(a, *(const short8*)(wp + 32 * 512 + k0), a2);
          a3 = MFMA_B16(a, *(const short8*)(wp + 48 * 512 + k0), a3);
        }
        f32x4 acc[4] = {a0, a1, a2, a3};
        #pragma unroll
        for (int tl = 0; tl < 4; ++tl) {
          int n = ws64 + tl * 16 + lane15;
          #pragma unroll
          for (int rg = 0; rg < 4; ++rg) {
            int m = (q8 >> 1) + rg;
            float h = bf2f(h1A[m * HS + n]);
            h1A[m * HS + n] = f2bf(acc[tl][rg] * (1.f - h * h));
          }
        }
      }
      __syncthreads();

      // ---- GEMM5b: gz = g1 @ W1y^T (N=64, K split 8 ways), l = sum(gz*eps) ----
      {
        f32x4 a0 = {0,0,0,0}, a1 = {0,0,0,0}, a2 = {0,0,0,0}, a3 = {0,0,0,0};
        const unsigned short* ap = h1A + lane15 * HS + ws64 + q8;
        const unsigned short* wp = W1y + (size_t)lane15 * 512 + ws64 + q8;
        #pragma unroll
        for (int kk = 0; kk < 64; kk += 32) {
          short8 a = *(const short8*)(ap + kk);
          a0 = MFMA_B16(a, *(const short8*)(wp + kk),            a0);
          a1 = MFMA_B16(a, *(const short8*)(wp + 16 * 512 + kk), a1);
          a2 = MFMA_B16(a, *(const short8*)(wp + 32 * 512 + kk), a2);
          a3 = MFMA_B16(a, *(const short8*)(wp + 48 * 512 + kk), a3);
        }
        f32x4 acc[4] = {a0, a1, a2, a3};
        if (lane < 32) {   // C rows 0..7 only
          #pragma unroll
          for (int rg = 0; rg < 4; ++rg) {
            int m = (q8 >> 1) + rg;
            float p = acc[0][rg] * eps_s[m][lane15]
                    + acc[1][rg] * eps_s[m][16 + lane15]
                    + acc[2][rg] * eps_s[m][32 + lane15]
                    + acc[3][rg] * eps_s[m][48 + lane15];
            #pragma unroll
            for (int o = 1; o < 16; o <<= 1) p += __shfl_xor(p, o);
            if (lane15 == 0) atomicAdd(&l_row[m], p);
          }
        }
      }
      __syncthreads();

      // ---- RK4 update (thread owns (tm,td)) ----
      {
        const float wk = (s == 0 || s == 3) ? w06 : w13;
        float fv = f_s[tm][td] + b3b[td];
        if (s == 0)      yacc[tm][td] = ycur[tm][td] + w06 * fv;
        else if (s < 3)  yacc[tm][td] += wk * fv;
        if (s < 3) {
          ytmp[tm][td] = ycur[tm][td] + ((s == 2) ? dt : 0.5f * dt) * fv;
        } else {
          float yn = yacc[tm][td] + w06 * fv;
          ycur[tm][td] = yn; ytmp[tm][td] = yn;
        }
        if (t < 8) {
          float lv = l_row[t];
          if (s == 0)      ldacc[t] = w06 * lv;
          else if (s < 3)  ldacc[t] += wk * lv;
          else             ld_row[t] += ldacc[t] + w06 * lv;
        }
      }
      __syncthreads();
    }
  }

  out[(size_t)(row0 + tm) * 65 + td] = ycur[tm][td];
  if (t < 8) out[(size_t)(row0 + t) * 65 + 64] = ld_row[t];
}

extern "C" void kernel_launch(void* const* d_in, const int* in_sizes, int n_in,
                              void* d_out, int out_size, void* d_ws, size_t ws_size,
                              hipStream_t stream) {
  (void)in_sizes; (void)n_in; (void)out_size; (void)ws_size;
  const float* x    = (const float*)d_in[0];
  const float* cond = (const float*)d_in[1];
  const float* eps  = (const float*)d_in[2];
  const float* W1   = (const float*)d_in[3];
  const float* b1   = (const float*)d_in[4];
  const float* W2   = (const float*)d_in[5];
  const float* b2   = (const float*)d_in[6];
  const float* W3   = (const float*)d_in[7];
  const float* b3   = (const float*)d_in[8];
  float* out = (float*)d_out;
  unsigned short* ws = (unsigned short*)d_ws;

  const int prep_total = 1343488;
  prep_bf16<<<(prep_total + 255) / 256, 256, 0, stream>>>(W1, W2, W3, ws);
  ffjord_mfma<<<512, 512, 0, stream>>>(x, cond, eps, b1, b2, b3, ws, out);
}

// Round 5
// 3377.358 us; speedup vs baseline: 1.4308x; 1.4308x over previous
//
#include <hip/hip_runtime.h>

// FFJORD B=4096 D=64 C=16 H=512, NBIJ=2, NSTEPS=8 RK4 -> 64 sequential MLP+VJP evals.
// Round 5: R2 shape (grid 256, M=16, 512 thr, 8 waves) + async global_load_lds staging
// for strip-GEMM weights (GEMM1/2/3b/4b), double-buffered 4KB chunks per wave with
// fine-grained vmcnt(4) waits. Each DMA = 1KB/wave, 8 outstanding -> 64KB/CU in flight.

typedef __attribute__((ext_vector_type(8))) short short8;
typedef __attribute__((ext_vector_type(4))) float f32x4;

#define MFMA_B16(a, b, c) __builtin_amdgcn_mfma_f32_16x16x32_bf16((a), (b), (c), 0, 0, 0)
#define AS1 __attribute__((address_space(1)))
#define AS3 __attribute__((address_space(3)))
#define WAIT_VM4  asm volatile("s_waitcnt vmcnt(4)" ::: "memory")
#define WAIT_VM0  asm volatile("s_waitcnt vmcnt(0)" ::: "memory")
#define WAIT_LGKM asm volatile("s_waitcnt lgkmcnt(0)" ::: "memory")

__device__ __forceinline__ unsigned short f2bf(float f) {
  union { float f; unsigned u; } v; v.f = f;
  return (unsigned short)((v.u + 0x7FFFu + ((v.u >> 16) & 1u)) >> 16);
}
__device__ __forceinline__ float bf2f(unsigned short u) {
  union { unsigned u; float f; } v; v.u = ((unsigned)u) << 16; return v.f;
}
__device__ __forceinline__ float fast_tanh(float x) {
  float e = __expf(2.f * x);
  return 1.f - 2.f * __builtin_amdgcn_rcpf(e + 1.f);
}
__device__ __forceinline__ void dma16(const unsigned short* g, char* l) {
  __builtin_amdgcn_global_load_lds((const AS1 unsigned int*)g, (AS3 unsigned int*)l, 16, 0, 0);
}
// one 4KB chunk = 4 x 1KB DMA; g already offset by lane*8 elems; l wave-uniform
__device__ __forceinline__ void dma_chunk(const unsigned short* g, char* l) {
  dma16(g, l);
  dma16(g + 512, l + 1024);
  dma16(g + 1024, l + 2048);
  dma16(g + 1536, l + 3072);
}

// ws layout (ushort units):
// W1f [2][8w][3kc][64c][32kk] @ 0        chunked (k>=81 zero-padded; strip=6144)
// W2f [2][8w][16kc][64c][32kk] @ 98304   chunked, B = W2^T   (strip=32768)
// W2b [2][8w][16kc][64c][32kk] @ 622592  chunked, B = W2     (strip=32768)
// W3f [2][64n][512k] @ 1146880           plain (register loads)
// W3b [2][8w][2kc][64c][32kk] @ 1212416  chunked, B = W3     (strip=4096)
// W1y [2][64n][512k] @ 1277952           plain (register loads)

__global__ void prep_bf16(const float* __restrict__ W1, const float* __restrict__ W2,
                          const float* __restrict__ W3, unsigned short* __restrict__ ws) {
  int o = blockIdx.x * 256 + threadIdx.x;
  if (o < 98304) {                       // W1f chunked
    int ib = o / 49152, r = o % 49152;
    int w = r / 6144, r2 = r % 6144;
    int kc = r2 / 2048, r3 = r2 % 2048;
    int c = r3 >> 5, kk = r3 & 31;
    int n = w * 64 + c, k = kc * 32 + kk;
    ws[o] = (k < 81) ? f2bf(W1[(size_t)ib * 41472 + k * 512 + n]) : (unsigned short)0;
  } else if (o < 622592) {               // W2f chunked (B = W2^T)
    int o2 = o - 98304;
    int ib = o2 >> 18, r = o2 & 262143;
    int w = r >> 15, r2 = r & 32767;
    int kc = r2 >> 11, r3 = r2 & 2047;
    int c = r3 >> 5, kk = r3 & 31;
    ws[o] = f2bf(W2[(size_t)ib * 262144 + (kc * 32 + kk) * 512 + w * 64 + c]);
  } else if (o < 1146880) {              // W2b chunked (B = W2)
    int o2 = o - 622592;
    int ib = o2 >> 18, r = o2 & 262143;
    int w = r >> 15, r2 = r & 32767;
    int kc = r2 >> 11, r3 = r2 & 2047;
    int c = r3 >> 5, kk = r3 & 31;
    ws[o] = f2bf(W2[(size_t)ib * 262144 + (w * 64 + c) * 512 + kc * 32 + kk]);
  } else if (o < 1212416) {              // W3f plain [n][k]
    int o2 = o - 1146880;
    int ib = o2 / 32768, r = o2 % 32768, n = r / 512, k = r % 512;
    ws[o] = f2bf(W3[(size_t)ib * 32768 + k * 64 + n]);
  } else if (o < 1277952) {              // W3b chunked (B = W3, n in H, k in D)
    int o2 = o - 1212416;
    int ib = o2 / 32768, r = o2 % 32768;
    int w = r / 4096, r2 = r % 4096;
    int kc = r2 >> 11, r3 = r2 & 2047;
    int c = r3 >> 5, kk = r3 & 31;
    ws[o] = f2bf(W3[(size_t)ib * 32768 + (w * 64 + c) * 64 + kc * 32 + kk]);
  } else if (o < 1343488) {              // W1y plain [n][k]
    int o2 = o - 1277952;
    int ib = o2 / 32768, r = o2 % 32768, n = r / 512, k = r % 512;
    ws[o] = f2bf(W1[(size_t)ib * 41472 + n * 512 + k]);
  }
}

#define ZS 104   // z A-buffer stride (K=96 used)
#define HS 520   // h buffers stride (K=512)
#define ES 72    // eps stride (K=64)

__global__ __launch_bounds__(512) void ffjord_mfma(
    const float* __restrict__ x, const float* __restrict__ cond, const float* __restrict__ eps,
    const float* __restrict__ b1g, const float* __restrict__ b2g, const float* __restrict__ b3g,
    const unsigned short* __restrict__ ws, float* __restrict__ out) {
  __shared__ unsigned short zA[16 * ZS];
  __shared__ unsigned short h1A[16 * HS];   // h1; overwritten by g1 in GEMM4b
  __shared__ unsigned short h2A[16 * HS];
  __shared__ unsigned short g2A[16 * HS];
  __shared__ unsigned short epsA[16 * ES];
  __shared__ __align__(16) char stageC[65536];   // 8 waves x 2 bufs x 4KB
  __shared__ float eps_s[16][64];
  __shared__ float f_s[16][64];
  __shared__ float ycur[16][64], ytmp[16][64], yacc[16][64];
  __shared__ float l_row[16], ld_row[16], ldacc[16];

  const int t = threadIdx.x;
  const int wave = t >> 6;
  const int lane = t & 63;
  const int lane15 = lane & 15;
  const int q8 = (lane >> 4) * 8;       // frag k-offset; C/D row base = q8>>1
  const int row0 = blockIdx.x * 16;
  const int ws64 = wave * 64;
  const int tm = t >> 6, td = t & 63;
  const int boff = lane15 * 64 + (q8 << 1);   // byte offset of b-frag within a 4KB chunk
  char* stw = stageC + wave * 8192;

  // init
  for (int e = t; e < 1024; e += 512) {
    int m = e >> 6, d = e & 63;
    float xv = x[(size_t)(row0 + m) * 64 + d];
    ycur[m][d] = xv; ytmp[m][d] = xv;
  }
  {
    int m = t >> 5, kk = t & 31;
    zA[m * ZS + 64 + kk] = (kk < 16) ? f2bf(cond[(size_t)(row0 + m) * 16 + kk]) : (unsigned short)0;
  }
  if (t < 16) ld_row[t] = 0.f;

  const float dt = 0.125f;
  const float w06 = dt / 6.f, w13 = dt / 3.f;

  for (int ib = 0; ib < 2; ++ib) {
    const unsigned short* W1f = ws + 0       + ib * 49152;
    const unsigned short* W2f = ws + 98304   + ib * 262144;
    const unsigned short* W2b = ws + 622592  + ib * 262144;
    const unsigned short* W3f = ws + 1146880 + ib * 32768;
    const unsigned short* W3b = ws + 1212416 + ib * 32768;
    const unsigned short* W1y = ws + 1277952 + ib * 32768;
    const float* b1b = b1g + ib * 512;
    const float* b2b = b2g + ib * 512;
    const float* b3b = b3g + ib * 64;

    for (int e = t; e < 1024; e += 512) {
      int m = e >> 6, d = e & 63;
      float ev = eps[((size_t)ib * 4096 + row0 + m) * 64 + d];
      eps_s[m][d] = ev;
      epsA[m * ES + d] = f2bf(ev);
    }
    __syncthreads();

    for (int it = 0; it < 32; ++it) {
      const int s = it & 3;
      const float te = (it >> 2) * dt + ((s == 0) ? 0.f : (s == 3) ? dt : 0.5f * dt);

      // ---- z build + zero accumulators ----
      for (int e = t; e < 1024; e += 512) {
        int m = e >> 6, d = e & 63;
        zA[m * ZS + d] = f2bf(ytmp[m][d]);
        f_s[m][d] = 0.f;
      }
      if (t < 16) { zA[t * ZS + 80] = f2bf(te); l_row[t] = 0.f; }
      __syncthreads();

      // ---- GEMM1 (staged, 3 chunks): h1 = tanh(z @ W1 + b1), K=96, N=512 ----
      {
        f32x4 a0 = {0,0,0,0}, a1 = {0,0,0,0}, a2 = {0,0,0,0}, a3 = {0,0,0,0};
        const unsigned short* gl = W1f + (size_t)wave * 6144 + lane * 8;
        dma_chunk(gl, stw);
        dma_chunk(gl + 2048, stw + 4096);
        const unsigned short* ah = zA + lane15 * ZS + q8;
        #pragma unroll
        for (int kc = 0; kc < 3; ++kc) {
          if (kc < 2) { WAIT_VM4; } else { WAIT_VM0; }
          const char* bp = stw + (kc & 1) * 4096 + boff;
          short8 a = *(const short8*)(ah + kc * 32);
          short8 b0 = *(const short8*)(bp);
          short8 b1 = *(const short8*)(bp + 1024);
          short8 b2v = *(const short8*)(bp + 2048);
          short8 b3v = *(const short8*)(bp + 3072);
          a0 = MFMA_B16(a, b0, a0);  a1 = MFMA_B16(a, b1, a1);
          a2 = MFMA_B16(a, b2v, a2); a3 = MFMA_B16(a, b3v, a3);
          if (kc == 0) { WAIT_LGKM; dma_chunk(gl + 4096, stw); }
        }
        f32x4 acc[4] = {a0, a1, a2, a3};
        #pragma unroll
        for (int tl = 0; tl < 4; ++tl) {
          int n = ws64 + tl * 16 + lane15;
          float bias = b1b[n];
          #pragma unroll
          for (int rg = 0; rg < 4; ++rg)
            h1A[((q8 >> 1) + rg) * HS + n] = f2bf(fast_tanh(acc[tl][rg] + bias));
        }
      }
      __syncthreads();

      // ---- GEMM2 (staged, 16 chunks): h2 = tanh(h1 @ W2 + b2), K=512, N=512 ----
      {
        f32x4 a0 = {0,0,0,0}, a1 = {0,0,0,0}, a2 = {0,0,0,0}, a3 = {0,0,0,0};
        const unsigned short* gl = W2f + (size_t)wave * 32768 + lane * 8;
        dma_chunk(gl, stw);
        dma_chunk(gl + 2048, stw + 4096);
        const unsigned short* ah = h1A + lane15 * HS + q8;
        #pragma unroll
        for (int kc = 0; kc < 16; ++kc) {
          if (kc < 15) { WAIT_VM4; } else { WAIT_VM0; }
          const char* bp = stw + (kc & 1) * 4096 + boff;
          short8 a = *(const short8*)(ah + kc * 32);
          short8 b0 = *(const short8*)(bp);
          short8 b1 = *(const short8*)(bp + 1024);
          short8 b2v = *(const short8*)(bp + 2048);
          short8 b3v = *(const short8*)(bp + 3072);
          a0 = MFMA_B16(a, b0, a0);  a1 = MFMA_B16(a, b1, a1);
          a2 = MFMA_B16(a, b2v, a2); a3 = MFMA_B16(a, b3v, a3);
          if (kc < 14) { WAIT_LGKM; dma_chunk(gl + (kc + 2) * 2048, stw + (kc & 1) * 4096); }
        }
        f32x4 acc[4] = {a0, a1, a2, a3};
        #pragma unroll
        for (int tl = 0; tl < 4; ++tl) {
          int n = ws64 + tl * 16 + lane15;
          float bias = b2b[n];
          #pragma unroll
          for (int rg = 0; rg < 4; ++rg)
            h2A[((q8 >> 1) + rg) * HS + n] = f2bf(fast_tanh(acc[tl][rg] + bias));
        }
      }
      __syncthreads();

      // ---- GEMM3b (staged, 2 chunks) FIRST: g2 = (eps @ W3^T) * (1 - h2^2), N=512, K=64 ----
      {
        f32x4 a0 = {0,0,0,0}, a1 = {0,0,0,0}, a2 = {0,0,0,0}, a3 = {0,0,0,0};
        const unsigned short* gl = W3b + (size_t)wave * 4096 + lane * 8;
        dma_chunk(gl, stw);
        dma_chunk(gl + 2048, stw + 4096);
        const unsigned short* ah = epsA + lane15 * ES + q8;
        #pragma unroll
        for (int kc = 0; kc < 2; ++kc) {
          if (kc < 1) { WAIT_VM4; } else { WAIT_VM0; }
          const char* bp = stw + kc * 4096 + boff;
          short8 a = *(const short8*)(ah + kc * 32);
          short8 b0 = *(const short8*)(bp);
          short8 b1 = *(const short8*)(bp + 1024);
          short8 b2v = *(const short8*)(bp + 2048);
          short8 b3v = *(const short8*)(bp + 3072);
          a0 = MFMA_B16(a, b0, a0);  a1 = MFMA_B16(a, b1, a1);
          a2 = MFMA_B16(a, b2v, a2); a3 = MFMA_B16(a, b3v, a3);
        }
        f32x4 acc[4] = {a0, a1, a2, a3};
        #pragma unroll
        for (int tl = 0; tl < 4; ++tl) {
          int n = ws64 + tl * 16 + lane15;
          #pragma unroll
          for (int rg = 0; rg < 4; ++rg) {
            int m = (q8 >> 1) + rg;
            float h = bf2f(h2A[m * HS + n]);
            g2A[m * HS + n] = f2bf(acc[tl][rg] * (1.f - h * h));
          }
        }
      }
      // ---- GEMM3f (register loads): f += h2 @ W3f (N=64, K split 8 ways x 64) ----
      {
        f32x4 a0 = {0,0,0,0}, a1 = {0,0,0,0}, a2 = {0,0,0,0}, a3 = {0,0,0,0};
        const unsigned short* ap = h2A + lane15 * HS + ws64 + q8;
        const unsigned short* wp = W3f + (size_t)lane15 * 512 + ws64 + q8;
        #pragma unroll
        for (int kk = 0; kk < 64; kk += 32) {
          short8 a = *(const short8*)(ap + kk);
          a0 = MFMA_B16(a, *(const short8*)(wp + kk),            a0);
          a1 = MFMA_B16(a, *(const short8*)(wp + 16 * 512 + kk), a1);
          a2 = MFMA_B16(a, *(const short8*)(wp + 32 * 512 + kk), a2);
          a3 = MFMA_B16(a, *(const short8*)(wp + 48 * 512 + kk), a3);
        }
        f32x4 acc[4] = {a0, a1, a2, a3};
        #pragma unroll
        for (int tl = 0; tl < 4; ++tl)
          #pragma unroll
          for (int rg = 0; rg < 4; ++rg)
            atomicAdd(&f_s[(q8 >> 1) + rg][tl * 16 + lane15], acc[tl][rg]);
      }
      __syncthreads();

      // ---- GEMM4b (staged, 16 chunks): g1 = (g2 @ W2^T) * (1 - h1^2) -> h1A in place ----
      {
        f32x4 a0 = {0,0,0,0}, a1 = {0,0,0,0}, a2 = {0,0,0,0}, a3 = {0,0,0,0};
        const unsigned short* gl = W2b + (size_t)wave * 32768 + lane * 8;
        dma_chunk(gl, stw);
        dma_chunk(gl + 2048, stw + 4096);
        const unsigned short* ah = g2A + lane15 * HS + q8;
        #pragma unroll
        for (int kc = 0; kc < 16; ++kc) {
          if (kc < 15) { WAIT_VM4; } else { WAIT_VM0; }
          const char* bp = stw + (kc & 1) * 4096 + boff;
          short8 a = *(const short8*)(ah + kc * 32);
          short8 b0 = *(const short8*)(bp);
          short8 b1 = *(const short8*)(bp + 1024);
          short8 b2v = *(const short8*)(bp + 2048);
          short8 b3v = *(const short8*)(bp + 3072);
          a0 = MFMA_B16(a, b0, a0);  a1 = MFMA_B16(a, b1, a1);
          a2 = MFMA_B16(a, b2v, a2); a3 = MFMA_B16(a, b3v, a3);
          if (kc < 14) { WAIT_LGKM; dma_chunk(gl + (kc + 2) * 2048, stw + (kc & 1) * 4096); }
        }
        f32x4 acc[4] = {a0, a1, a2, a3};
        #pragma unroll
        for (int tl = 0; tl < 4; ++tl) {
          int n = ws64 + tl * 16 + lane15;
          #pragma unroll
          for (int rg = 0; rg < 4; ++rg) {
            int m = (q8 >> 1) + rg;
            float h = bf2f(h1A[m * HS + n]);
            h1A[m * HS + n] = f2bf(acc[tl][rg] * (1.f - h * h));
          }
        }
      }
      __syncthreads();

      // ---- GEMM5b (register loads): gz = g1 @ W1y^T (N=64, K split 8 ways), l = sum(gz*eps) ----
      {
        f32x4 a0 = {0,0,0,0}, a1 = {0,0,0,0}, a2 = {0,0,0,0}, a3 = {0,0,0,0};
        const unsigned short* ap = h1A + lane15 * HS + ws64 + q8;
        const unsigned short* wp = W1y + (size_t)lane15 * 512 + ws64 + q8;
        #pragma unroll
        for (int kk = 0; kk < 64; kk += 32) {
          short8 a = *(const short8*)(ap + kk);
          a0 = MFMA_B16(a, *(const short8*)(wp + kk),            a0);
          a1 = MFMA_B16(a, *(const short8*)(wp + 16 * 512 + kk), a1);
          a2 = MFMA_B16(a, *(const short8*)(wp + 32 * 512 + kk), a2);
          a3 = MFMA_B16(a, *(const short8*)(wp + 48 * 512 + kk), a3);
        }
        f32x4 acc[4] = {a0, a1, a2, a3};
        #pragma unroll
        for (int rg = 0; rg < 4; ++rg) {
          int m = (q8 >> 1) + rg;
          float p = acc[0][rg] * eps_s[m][lane15]
                  + acc[1][rg] * eps_s[m][16 + lane15]
                  + acc[2][rg] * eps_s[m][32 + lane15]
                  + acc[3][rg] * eps_s[m][48 + lane15];
          #pragma unroll
          for (int o = 1; o < 16; o <<= 1) p += __shfl_xor(p, o);
          if (lane15 == 0) atomicAdd(&l_row[m], p);
        }
      }
      __syncthreads();

      // ---- RK4 update ----
      {
        const float wk = (s == 0 || s == 3) ? w06 : w13;
        for (int e = t; e < 1024; e += 512) {
          int m = e >> 6, d = e & 63;
          float fv = f_s[m][d] + b3b[d];
          if (s == 0)      yacc[m][d] = ycur[m][d] + w06 * fv;
          else if (s < 3)  yacc[m][d] += wk * fv;
          if (s < 3) {
            ytmp[m][d] = ycur[m][d] + ((s == 2) ? dt : 0.5f * dt) * fv;
          } else {
            float yn = yacc[m][d] + w06 * fv;
            ycur[m][d] = yn; ytmp[m][d] = yn;
          }
        }
        if (t < 16) {
          float lv = l_row[t];
          if (s == 0)      ldacc[t] = w06 * lv;
          else if (s < 3)  ldacc[t] += wk * lv;
          else             ld_row[t] += ldacc[t] + w06 * lv;
        }
      }
      __syncthreads();
    }
  }

  for (int e = t; e < 1024; e += 512) {
    int m = e >> 6, d = e & 63;
    out[(size_t)(row0 + m) * 65 + d] = ycur[m][d];
  }
  if (t < 16) out[(size_t)(row0 + t) * 65 + 64] = ld_row[t];
}

extern "C" void kernel_launch(void* const* d_in, const int* in_sizes, int n_in,
                              void* d_out, int out_size, void* d_ws, size_t ws_size,
                              hipStream_t stream) {
  (void)in_sizes; (void)n_in; (void)out_size; (void)ws_size;
  const float* x    = (const float*)d_in[0];
  const float* cond = (const float*)d_in[1];
  const float* eps  = (const float*)d_in[2];
  const float* W1   = (const float*)d_in[3];
  const float* b1   = (const float*)d_in[4];
  const float* W2   = (const float*)d_in[5];
  const float* b2   = (const float*)d_in[6];
  const float* W3   = (const float*)d_in[7];
  const float* b3   = (const float*)d_in[8];
  float* out = (float*)d_out;
  unsigned short* ws = (unsigned short*)d_ws;

  const int prep_total = 1343488;
  prep_bf16<<<(prep_total + 255) / 256, 256, 0, stream>>>(W1, W2, W3, ws);
  ffjord_mfma<<<256, 512, 0, stream>>>(x, cond, eps, b1, b2, b3, ws, out);
}

// Round 6
// 2772.924 us; speedup vs baseline: 1.7426x; 1.2180x over previous
//
#include <hip/hip_runtime.h>

// FFJORD B=4096 D=64 C=16 H=512, NBIJ=2, NSTEPS=8 RK4 -> 64 sequential MLP+VJP evals.
// Round 6: R2 shape (grid 256, M=16, 512 thr, 8 waves, register-loaded weights) +
//  (1) unroll-8 K-loops on the two 512KB GEMMs (deeper VMEM pipeline; regs<=240/wave is
//      free at 1 block/CU), (2) e3 = eps@W3^T hoisted out of the eval loop (constant per
//      bijector) -> per-eval g2 is elementwise, -64KB/eval traffic, bit-identical math.

typedef __attribute__((ext_vector_type(8))) short short8;
typedef __attribute__((ext_vector_type(4))) float f32x4;

#define MFMA_B16(a, b, c) __builtin_amdgcn_mfma_f32_16x16x32_bf16((a), (b), (c), 0, 0, 0)

__device__ __forceinline__ unsigned short f2bf(float f) {
  union { float f; unsigned u; } v; v.f = f;
  return (unsigned short)((v.u + 0x7FFFu + ((v.u >> 16) & 1u)) >> 16);
}
__device__ __forceinline__ float bf2f(unsigned short u) {
  union { unsigned u; float f; } v; v.u = ((unsigned)u) << 16; return v.f;
}
__device__ __forceinline__ float fast_tanh(float x) {
  float e = __expf(2.f * x);
  return 1.f - 2.f * __builtin_amdgcn_rcpf(e + 1.f);
}

// ws layout (ushort units), all bf16 column-major W[n][k]:
// W1f [2][512][96]  @ 0        (k>=81 zero-padded)
// W2f [2][512][512] @ 98304    (W2^T data: forward B)
// W2b [2][512][512] @ 622592   (plain W2: backward B)
// W3f [2][64][512]  @ 1146880  (W3^T: forward B)
// W3b [2][512][64]  @ 1212416  (plain W3: B for e3 = eps@W3^T, used once per bijector)
// W1y [2][64][512]  @ 1277952  (first 64 rows of W1)

__global__ void prep_bf16(const float* __restrict__ W1, const float* __restrict__ W2,
                          const float* __restrict__ W3, unsigned short* __restrict__ ws) {
  int o = blockIdx.x * 256 + threadIdx.x;
  if (o < 98304) {
    int ib = o / 49152, r = o % 49152, n = r / 96, k = r % 96;
    ws[o] = (k < 81) ? f2bf(W1[(size_t)ib * 41472 + k * 512 + n]) : (unsigned short)0;
  } else if (o < 622592) {
    int o2 = o - 98304;
    int ib = o2 / 262144, r = o2 % 262144, n = r / 512, k = r % 512;
    ws[o] = f2bf(W2[(size_t)ib * 262144 + k * 512 + n]);
  } else if (o < 1146880) {
    ws[o] = f2bf(W2[o - 622592]);
  } else if (o < 1212416) {
    int o2 = o - 1146880;
    int ib = o2 / 32768, r = o2 % 32768, n = r / 512, k = r % 512;
    ws[o] = f2bf(W3[(size_t)ib * 32768 + k * 64 + n]);
  } else if (o < 1277952) {
    ws[o] = f2bf(W3[o - 1212416]);
  } else if (o < 1343488) {
    int o2 = o - 1277952;
    int ib = o2 / 32768, r = o2 % 32768, n = r / 512, k = r % 512;
    ws[o] = f2bf(W1[(size_t)ib * 41472 + n * 512 + k]);
  }
}

#define ZS 104   // z A-buffer stride (K=96 used)
#define HS 520   // h buffers stride (K=512)
#define ES 72    // eps stride (K=64)

__global__ __launch_bounds__(512) void ffjord_mfma(
    const float* __restrict__ x, const float* __restrict__ cond, const float* __restrict__ eps,
    const float* __restrict__ b1g, const float* __restrict__ b2g, const float* __restrict__ b3g,
    const unsigned short* __restrict__ ws, float* __restrict__ out) {
  __shared__ unsigned short zA[16 * ZS];
  __shared__ unsigned short h1A[16 * HS];   // h1; overwritten by g1 in GEMM4b
  __shared__ unsigned short h2A[16 * HS];
  __shared__ unsigned short g2A[16 * HS];
  __shared__ unsigned short e3A[16 * HS];   // e3 = eps @ W3^T, constant per bijector
  __shared__ unsigned short epsA[16 * ES];
  __shared__ float eps_s[16][64];
  __shared__ float f_s[16][64];
  __shared__ float ycur[16][64], ytmp[16][64], yacc[16][64];
  __shared__ float l_row[16], ld_row[16], ldacc[16];

  const int t = threadIdx.x;
  const int wave = t >> 6;
  const int lane = t & 63;
  const int lane15 = lane & 15;
  const int q8 = (lane >> 4) * 8;       // frag k-offset; C/D row base = q8>>1
  const int row0 = blockIdx.x * 16;
  const int ws64 = wave * 64;
  const int tm = t >> 6, td = t & 63;

  // init
  for (int e = t; e < 1024; e += 512) {
    int m = e >> 6, d = e & 63;
    float xv = x[(size_t)(row0 + m) * 64 + d];
    ycur[m][d] = xv; ytmp[m][d] = xv;
  }
  {
    int m = t >> 5, kk = t & 31;
    zA[m * ZS + 64 + kk] = (kk < 16) ? f2bf(cond[(size_t)(row0 + m) * 16 + kk]) : (unsigned short)0;
  }
  if (t < 16) ld_row[t] = 0.f;

  const float dt = 0.125f;
  const float w06 = dt / 6.f, w13 = dt / 3.f;

  for (int ib = 0; ib < 2; ++ib) {
    const unsigned short* W1f = ws + 0       + ib * 49152;
    const unsigned short* W2f = ws + 98304   + ib * 262144;
    const unsigned short* W2b = ws + 622592  + ib * 262144;
    const unsigned short* W3f = ws + 1146880 + ib * 32768;
    const unsigned short* W3b = ws + 1212416 + ib * 32768;
    const unsigned short* W1y = ws + 1277952 + ib * 32768;
    const float* b1b = b1g + ib * 512;
    const float* b2b = b2g + ib * 512;
    const float* b3b = b3g + ib * 64;

    for (int e = t; e < 1024; e += 512) {
      int m = e >> 6, d = e & 63;
      float ev = eps[((size_t)ib * 4096 + row0 + m) * 64 + d];
      eps_s[m][d] = ev;
      epsA[m * ES + d] = f2bf(ev);
    }
    __syncthreads();

    // ---- e3 = eps @ W3^T (N=512, K=64), ONCE per bijector ----
    {
      f32x4 a0 = {0,0,0,0}, a1 = {0,0,0,0}, a2 = {0,0,0,0}, a3 = {0,0,0,0};
      const unsigned short* ap = epsA + lane15 * ES + q8;
      const unsigned short* wp = W3b + (size_t)(ws64 + lane15) * 64 + q8;
      #pragma unroll
      for (int kk = 0; kk < 64; kk += 32) {
        short8 a = *(const short8*)(ap + kk);
        a0 = MFMA_B16(a, *(const short8*)(wp + kk),           a0);
        a1 = MFMA_B16(a, *(const short8*)(wp + 16 * 64 + kk), a1);
        a2 = MFMA_B16(a, *(const short8*)(wp + 32 * 64 + kk), a2);
        a3 = MFMA_B16(a, *(const short8*)(wp + 48 * 64 + kk), a3);
      }
      f32x4 acc[4] = {a0, a1, a2, a3};
      #pragma unroll
      for (int tl = 0; tl < 4; ++tl) {
        int n = ws64 + tl * 16 + lane15;
        #pragma unroll
        for (int rg = 0; rg < 4; ++rg)
          e3A[((q8 >> 1) + rg) * HS + n] = f2bf(acc[tl][rg]);
      }
    }
    __syncthreads();

    for (int it = 0; it < 32; ++it) {
      const int s = it & 3;
      const float te = (it >> 2) * dt + ((s == 0) ? 0.f : (s == 3) ? dt : 0.5f * dt);

      // ---- z build + zero accumulators ----
      for (int e = t; e < 1024; e += 512) {
        int m = e >> 6, d = e & 63;
        zA[m * ZS + d] = f2bf(ytmp[m][d]);
        f_s[m][d] = 0.f;
      }
      if (t < 16) { zA[t * ZS + 80] = f2bf(te); l_row[t] = 0.f; }
      __syncthreads();

      // ---- GEMM1: h1 = tanh(z @ W1 + b1), K=96, N=512 ----
      {
        f32x4 a0 = {0,0,0,0}, a1 = {0,0,0,0}, a2 = {0,0,0,0}, a3 = {0,0,0,0};
        const unsigned short* ap = zA + lane15 * ZS + q8;
        const unsigned short* wp = W1f + (size_t)(ws64 + lane15) * 96 + q8;
        #pragma unroll
        for (int k0 = 0; k0 < 96; k0 += 32) {
          short8 a = *(const short8*)(ap + k0);
          a0 = MFMA_B16(a, *(const short8*)(wp + k0),           a0);
          a1 = MFMA_B16(a, *(const short8*)(wp + 16 * 96 + k0), a1);
          a2 = MFMA_B16(a, *(const short8*)(wp + 32 * 96 + k0), a2);
          a3 = MFMA_B16(a, *(const short8*)(wp + 48 * 96 + k0), a3);
        }
        f32x4 acc[4] = {a0, a1, a2, a3};
        #pragma unroll
        for (int tl = 0; tl < 4; ++tl) {
          int n = ws64 + tl * 16 + lane15;
          float bias = b1b[n];
          #pragma unroll
          for (int rg = 0; rg < 4; ++rg)
            h1A[((q8 >> 1) + rg) * HS + n] = f2bf(fast_tanh(acc[tl][rg] + bias));
        }
      }
      __syncthreads();

      // ---- GEMM2: h2 = tanh(h1 @ W2 + b2), K=512, N=512 (deep pipeline) ----
      {
        f32x4 a0 = {0,0,0,0}, a1 = {0,0,0,0}, a2 = {0,0,0,0}, a3 = {0,0,0,0};
        const unsigned short* ap = h1A + lane15 * HS + q8;
        const unsigned short* wp = W2f + (size_t)(ws64 + lane15) * 512 + q8;
        #pragma unroll 8
        for (int k0 = 0; k0 < 512; k0 += 32) {
          short8 a = *(const short8*)(ap + k0);
          a0 = MFMA_B16(a, *(const short8*)(wp + k0),            a0);
          a1 = MFMA_B16(a, *(const short8*)(wp + 16 * 512 + k0), a1);
          a2 = MFMA_B16(a, *(const short8*)(wp + 32 * 512 + k0), a2);
          a3 = MFMA_B16(a, *(const short8*)(wp + 48 * 512 + k0), a3);
        }
        f32x4 acc[4] = {a0, a1, a2, a3};
        #pragma unroll
        for (int tl = 0; tl < 4; ++tl) {
          int n = ws64 + tl * 16 + lane15;
          float bias = b2b[n];
          #pragma unroll
          for (int rg = 0; rg < 4; ++rg)
            h2A[((q8 >> 1) + rg) * HS + n] = f2bf(fast_tanh(acc[tl][rg] + bias));
        }
      }
      __syncthreads();

      // ---- g2 = e3 * (1 - h2^2), elementwise; GEMM3f: f += h2 @ W3f (K split 8 ways) ----
      {
        #pragma unroll
        for (int j = 0; j < 16; ++j) {
          int idx = t + j * 512;
          int m = idx >> 9, n = idx & 511;
          float h = bf2f(h2A[m * HS + n]);
          g2A[m * HS + n] = f2bf(bf2f(e3A[m * HS + n]) * (1.f - h * h));
        }
      }
      {
        f32x4 a0 = {0,0,0,0}, a1 = {0,0,0,0}, a2 = {0,0,0,0}, a3 = {0,0,0,0};
        const unsigned short* ap = h2A + lane15 * HS + ws64 + q8;
        const unsigned short* wp = W3f + (size_t)lane15 * 512 + ws64 + q8;
        #pragma unroll
        for (int kk = 0; kk < 64; kk += 32) {
          short8 a = *(const short8*)(ap + kk);
          a0 = MFMA_B16(a, *(const short8*)(wp + kk),            a0);
          a1 = MFMA_B16(a, *(const short8*)(wp + 16 * 512 + kk), a1);
          a2 = MFMA_B16(a, *(const short8*)(wp + 32 * 512 + kk), a2);
          a3 = MFMA_B16(a, *(const short8*)(wp + 48 * 512 + kk), a3);
        }
        f32x4 acc[4] = {a0, a1, a2, a3};
        #pragma unroll
        for (int tl = 0; tl < 4; ++tl)
          #pragma unroll
          for (int rg = 0; rg < 4; ++rg)
            atomicAdd(&f_s[(q8 >> 1) + rg][tl * 16 + lane15], acc[tl][rg]);
      }
      __syncthreads();

      // ---- GEMM4b: g1 = (g2 @ W2^T) * (1 - h1^2) -> h1A in place (deep pipeline) ----
      {
        f32x4 a0 = {0,0,0,0}, a1 = {0,0,0,0}, a2 = {0,0,0,0}, a3 = {0,0,0,0};
        const unsigned short* ap = g2A + lane15 * HS + q8;
        const unsigned short* wp = W2b + (size_t)(ws64 + lane15) * 512 + q8;
        #pragma unroll 8
        for (int k0 = 0; k0 < 512; k0 += 32) {
          short8 a = *(const short8*)(ap + k0);
          a0 = MFMA_B16(a, *(const short8*)(wp + k0),            a0);
          a1 = MFMA_B16(a, *(const short8*)(wp + 16 * 512 + k0), a1);
          a2 = MFMA_B16(a, *(const short8*)(wp + 32 * 512 + k0), a2);
          a3 = MFMA_B16(a, *(const short8*)(wp + 48 * 512 + k0), a3);
        }
        f32x4 acc[4] = {a0, a1, a2, a3};
        #pragma unroll
        for (int tl = 0; tl < 4; ++tl) {
          int n = ws64 + tl * 16 + lane15;
          #pragma unroll
          for (int rg = 0; rg < 4; ++rg) {
            int m = (q8 >> 1) + rg;
            float h = bf2f(h1A[m * HS + n]);
            h1A[m * HS + n] = f2bf(acc[tl][rg] * (1.f - h * h));
          }
        }
      }
      __syncthreads();

      // ---- GEMM5b: gz = g1 @ W1y^T (N=64, K split 8 ways), l = sum(gz*eps) ----
      {
        f32x4 a0 = {0,0,0,0}, a1 = {0,0,0,0}, a2 = {0,0,0,0}, a3 = {0,0,0,0};
        const unsigned short* ap = h1A + lane15 * HS + ws64 + q8;
        const unsigned short* wp = W1y + (size_t)lane15 * 512 + ws64 + q8;
        #pragma unroll
        for (int kk = 0; kk < 64; kk += 32) {
          short8 a = *(const short8*)(ap + kk);
          a0 = MFMA_B16(a, *(const short8*)(wp + kk),            a0);
          a1 = MFMA_B16(a, *(const short8*)(wp + 16 * 512 + kk), a1);
          a2 = MFMA_B16(a, *(const short8*)(wp + 32 * 512 + kk), a2);
          a3 = MFMA_B16(a, *(const short8*)(wp + 48 * 512 + kk), a3);
        }
        f32x4 acc[4] = {a0, a1, a2, a3};
        #pragma unroll
        for (int rg = 0; rg < 4; ++rg) {
          int m = (q8 >> 1) + rg;
          float p = acc[0][rg] * eps_s[m][lane15]
                  + acc[1][rg] * eps_s[m][16 + lane15]
                  + acc[2][rg] * eps_s[m][32 + lane15]
                  + acc[3][rg] * eps_s[m][48 + lane15];
          #pragma unroll
          for (int o = 1; o < 16; o <<= 1) p += __shfl_xor(p, o);
          if (lane15 == 0) atomicAdd(&l_row[m], p);
        }
      }
      __syncthreads();

      // ---- RK4 update ----
      {
        const float wk = (s == 0 || s == 3) ? w06 : w13;
        for (int e = t; e < 1024; e += 512) {
          int m = e >> 6, d = e & 63;
          float fv = f_s[m][d] + b3b[d];
          if (s == 0)      yacc[m][d] = ycur[m][d] + w06 * fv;
          else if (s < 3)  yacc[m][d] += wk * fv;
          if (s < 3) {
            ytmp[m][d] = ycur[m][d] + ((s == 2) ? dt : 0.5f * dt) * fv;
          } else {
            float yn = yacc[m][d] + w06 * fv;
            ycur[m][d] = yn; ytmp[m][d] = yn;
          }
        }
        if (t < 16) {
          float lv = l_row[t];
          if (s == 0)      ldacc[t] = w06 * lv;
          else if (s < 3)  ldacc[t] += wk * lv;
          else             ld_row[t] += ldacc[t] + w06 * lv;
        }
      }
      __syncthreads();
    }
  }

  for (int e = t; e < 1024; e += 512) {
    int m = e >> 6, d = e & 63;
    out[(size_t)(row0 + m) * 65 + d] = ycur[m][d];
  }
  if (t < 16) out[(size_t)(row0 + t) * 65 + 64] = ld_row[t];
}

extern "C" void kernel_launch(void* const* d_in, const int* in_sizes, int n_in,
                              void* d_out, int out_size, void* d_ws, size_t ws_size,
                              hipStream_t stream) {
  (void)in_sizes; (void)n_in; (void)out_size; (void)ws_size;
  const float* x    = (const float*)d_in[0];
  const float* cond = (const float*)d_in[1];
  const float* eps  = (const float*)d_in[2];
  const float* W1   = (const float*)d_in[3];
  const float* b1   = (const float*)d_in[4];
  const float* W2   = (const float*)d_in[5];
  const float* b2   = (const float*)d_in[6];
  const float* W3   = (const float*)d_in[7];
  const float* b3   = (const float*)d_in[8];
  float* out = (float*)d_out;
  unsigned short* ws = (unsigned short*)d_ws;

  const int prep_total = 1343488;
  prep_bf16<<<(prep_total + 255) / 256, 256, 0, stream>>>(W1, W2, W3, ws);
  ffjord_mfma<<<256, 512, 0, stream>>>(x, cond, eps, b1, b2, b3, ws, out);
}